// Round 19
// baseline (168.214 us; speedup 1.0000x reference)
//
#include <hip/hip_runtime.h>
#include <hip/hip_bf16.h>

// ModalAttention fused pipeline, MI355X (gfx950).
//
// Math: attn/|global_min| followed by L2-normalize cancels any positive
// per-tensor scale (incl. /sqrt(h)) -> softmax input = s_row/||s_row||_2,
// s = q.k. No global-min reduction needed.
//
// Round 19: qkv pushed one more notch along the TLP axis that produced
// r14->r15's win: 128x64 tiles, 4 waves (per-wave 32x64, acc[2][4]),
// 2-slot 24KB LDS = 48KB -> 3 BLOCKS/CU (144KB), 12 independent
// waves/CU. LDS traffic/MAC rises 1.5x (pipe was only ~40% utilized;
// floor ~46us) in exchange for 1.5x more latency-hiding parallelism.
// All panel/swizzle/lane-k formulas identical to the r12-proven core;
// r18 single-barrier phase. s/pv/softmax/ln/cvt = round-18 passing code.

typedef float f32x4 __attribute__((ext_vector_type(4)));
typedef int i32x4v __attribute__((ext_vector_type(4)));
typedef int i32x8v __attribute__((ext_vector_type(8)));

struct alignas(16) US8 { unsigned short s[8]; };
struct alignas(8)  US4 { unsigned short s[4]; };

// ---------------- workspace layout (bytes, disjoint) ----------------
#define WS_XB   0ull                        // data bf16 [16384][1024] 33.55MB
#define WS_XF8  33554432ull                 // data fp8  [16384][1024] 16.78MB
#define WS_WF8  50331648ull                 // wq,wk,wv fp8 [3][1024][1024] 3.15MB
#define WS_QF8  53477376ull                 // Q fp8 [16384][1024] 16.78MB
#define WS_KF8  70254592ull                 // K fp8 [16384][1024] 16.78MB
#define WS_VT8  87031808ull                 // V^T fp8 [32][1024][512] 16.78MB
#define WS_S8   103809024ull                // S fp8 [16384][512] 8.39MB
#define WS_P8   112197632ull                // P fp8 (x256) [16384][512] 8.39MB
#define WS_O8   120586240ull                // O fp8 (x16) [16384][1024] 16.78MB
#define WS_NEED 137363456ull

__device__ __forceinline__ unsigned short f32_to_bf16(float f) {
  unsigned int u = __builtin_bit_cast(unsigned int, f);
  u += 0x7fffu + ((u >> 16) & 1u);            // round-to-nearest-even
  return (unsigned short)(u >> 16);
}
__device__ __forceinline__ float bf16_to_f32(unsigned short h) {
  return __builtin_bit_cast(float, (unsigned int)h << 16);
}

__device__ __forceinline__ void gload_lds16(const void* g, void* lds) {
  __builtin_amdgcn_global_load_lds(
      (const __attribute__((address_space(1))) unsigned int*)g,
      (__attribute__((address_space(3))) unsigned int*)lds, 16, 0, 0);
}

__device__ __forceinline__ float wave_sum(float v) {
#pragma unroll
  for (int off = 32; off > 0; off >>= 1) v += __shfl_xor(v, off);
  return v;
}
__device__ __forceinline__ float wave_max(float v) {
#pragma unroll
  for (int off = 32; off > 0; off >>= 1) v = fmaxf(v, __shfl_xor(v, off));
  return v;
}

__device__ __forceinline__ unsigned int pk_fp8x4(float a, float b, float c, float d) {
  unsigned int v = 0;
  v = __builtin_amdgcn_cvt_pk_fp8_f32(a, b, v, false);  // bytes 0,1
  v = __builtin_amdgcn_cvt_pk_fp8_f32(c, d, v, true);   // bytes 2,3
  return v;
}
__device__ __forceinline__ unsigned char f32_to_fp8(float v) {
  return (unsigned char)(__builtin_amdgcn_cvt_pk_fp8_f32(v, v, 0, false) & 0xffu);
}
// exact e4m3 -> f32 (normals AND subnormals)
__device__ __forceinline__ float fp8_to_f32(unsigned int b) {
  unsigned int u = ((b & 0x80u) << 24) | ((b & 0x7Fu) << 20);
  return __builtin_bit_cast(float, u) * 0x1p120f;
}

// ------- merged cast: data f32->bf16+fp8, weights f32->fp8, one launch -----
__global__ __launch_bounds__(256) void cvt_all(const float* __restrict__ data,
                                               const float* __restrict__ wq,
                                               const float* __restrict__ wk,
                                               const float* __restrict__ wv,
                                               unsigned short* __restrict__ Xb,
                                               unsigned int* __restrict__ Xf8,
                                               unsigned int* __restrict__ Wf8) {
  const int bid = blockIdx.x;
  if (bid < 8192) {                 // data: 2097152 groups of 8
    int i = bid * 256 + threadIdx.x;
    const float4* sp = (const float4*)(data + (size_t)i * 8);
    float4 a = sp[0], b = sp[1];
    US8 u;
    u.s[0] = f32_to_bf16(a.x); u.s[1] = f32_to_bf16(a.y);
    u.s[2] = f32_to_bf16(a.z); u.s[3] = f32_to_bf16(a.w);
    u.s[4] = f32_to_bf16(b.x); u.s[5] = f32_to_bf16(b.y);
    u.s[6] = f32_to_bf16(b.z); u.s[7] = f32_to_bf16(b.w);
    *(US8*)(Xb + (size_t)i * 8) = u;
    uint2 w;
    w.x = pk_fp8x4(a.x, a.y, a.z, a.w);
    w.y = pk_fp8x4(b.x, b.y, b.z, b.w);
    *(uint2*)(Xf8 + (size_t)i * 2) = w;
  } else {                          // weights: 3 x 512 blocks
    const int r = bid - 8192;
    const int z = r >> 9;
    const float* src = (z == 0) ? wq : (z == 1) ? wk : wv;
    int i = (r & 511) * 256 + threadIdx.x;
    const float4* sp = (const float4*)(src + (size_t)i * 8);
    float4 a = sp[0], b = sp[1];
    uint2 w;
    w.x = pk_fp8x4(a.x, a.y, a.z, a.w);
    w.y = pk_fp8x4(b.x, b.y, b.z, b.w);
    *(uint2*)(Wf8 + (size_t)z * 262144 + (size_t)i * 2) = w;
  }
}

// ======== QKV: 128x64 tile fp8 K=128, 2-slot 24KB, 3 blocks/CU ========
// Grid 6144 (128 M-tiles x 48 N-tiles), 256 threads = 4 waves, per-wave
// 32x64 (acc[2][4]). LDS slot 24KB: Ap0[0,8K) Ap1[8K,16K) (128rows x
// 64B), Bp0[16K,20K) Bp1[20K,24K) (64 rows). Same swizzle formulas.
__global__ __launch_bounds__(256, 3) void qkv_64(
    const unsigned char* __restrict__ Xf8, const unsigned char* __restrict__ Wf8,
    unsigned char* __restrict__ Qf8, unsigned char* __restrict__ Kf8,
    unsigned char* __restrict__ Vt8) {
  __shared__ alignas(16) char smc[2][24576];

  const int tid = threadIdx.x;
  const int w = tid >> 6, lane = tid & 63;
  const int lr = lane & 15, lk4 = lane >> 4;

  // bijective XCD-chunked swizzle: 6144 blocks, 768 per XCD
  const int bid = blockIdx.x;
  const int wg = (bid & 7) * 768 + (bid >> 3);
  const int bm = wg / 48, bn = wg % 48;

  const char* Ag = (const char*)Xf8 + (size_t)bm * 128 * 1024;
  const char* Bg = (const char*)Wf8 + (size_t)bn * 64 * 1024;

  // staging: thread t -> row t>>2 (0..63), chunk t&3; src chunk swizzled
  const int sc = ((tid & 3) ^ ((tid >> 3) & 3)) * 16;
  const char* pA = Ag + (size_t)(tid >> 2) * 1024 + sc;
  const char* pB = Bg + (size_t)(tid >> 2) * 1024 + sc;

  // read: panel = lk4>>1; chunks c0=(lk4&1)*2, c0+1, swizzled by (lr>>1)&3
  const int swz = (lr >> 1) & 3;
  const int c0 = (lk4 & 1) * 2;
  const int cb0 = ((c0) ^ swz) * 16;
  const int cb1 = ((c0 + 1) ^ swz) * 16;
  const int panA = (lk4 >> 1) * 8192;
  const int panB = 16384 + (lk4 >> 1) * 4096;
  const int rowA = (w * 32 + lr) * 64;   // + m*1024 (m=0,1)
  const int rowB = lr * 64;              // + n*1024 (n=0..3)

  f32x4 acc[2][4] = {};

#define STAGE6(DD)                                                            \
  do {                                                                        \
    char* dd_ = (DD);                                                         \
    gload_lds16(pA,                 dd_ + tid * 16);                          \
    gload_lds16(pA + 65536,         dd_ + 4096 + tid * 16);                   \
    gload_lds16(pA + 64,            dd_ + 8192 + tid * 16);                   \
    gload_lds16(pA + 65536 + 64,    dd_ + 12288 + tid * 16);                  \
    gload_lds16(pB,                 dd_ + 16384 + tid * 16);                  \
    gload_lds16(pB + 64,            dd_ + 20480 + tid * 16);                  \
    pA += 128; pB += 128;                                                     \
  } while (0)

#define MK8(D, OFF)                                                           \
  do {                                                                        \
    i32x4v lo_ = *(const i32x4v*)(sp + (OFF) + cb0);                          \
    i32x4v hi_ = *(const i32x4v*)(sp + (OFF) + cb1);                          \
    D[0] = lo_[0]; D[1] = lo_[1]; D[2] = lo_[2]; D[3] = lo_[3];               \
    D[4] = hi_[0]; D[5] = hi_[1]; D[6] = hi_[2]; D[7] = hi_[3];               \
  } while (0)

#define MFMA128(ACC, AV, BV)                                                  \
  asm("v_mfma_f32_16x16x128_f8f6f4 %0, %1, %2, %0"                            \
      : "+a"(ACC) : "v"(AV), "v"(BV))

  STAGE6(smc[0]);   // prologue: K-tile 0 -> slot 0 (6 loads outstanding)

#pragma unroll
  for (int t = 0; t < 8; ++t) {
    const int slot = t & 1;
    asm volatile("s_waitcnt vmcnt(0)" ::: "memory");
    __builtin_amdgcn_s_barrier();
    __builtin_amdgcn_sched_barrier(0);
    if (t + 1 < 8) STAGE6(smc[slot ^ 1]);
    const char* sp = smc[slot];
    i32x8v a0, a1, b0, b1, b2, b3;
    MK8(a0, panA + rowA);          MK8(a1, panA + rowA + 1024);
    MK8(b0, panB + rowB);          MK8(b1, panB + rowB + 1024);
    MK8(b2, panB + rowB + 2048);   MK8(b3, panB + rowB + 3072);
    __builtin_amdgcn_s_setprio(1);
    MFMA128(acc[0][0], a0, b0); MFMA128(acc[0][1], a0, b1);
    MFMA128(acc[0][2], a0, b2); MFMA128(acc[0][3], a0, b3);
    MFMA128(acc[1][0], a1, b0); MFMA128(acc[1][1], a1, b1);
    MFMA128(acc[1][2], a1, b2); MFMA128(acc[1][3], a1, b3);
    __builtin_amdgcn_s_setprio(0);
    __builtin_amdgcn_sched_barrier(0);
  }

#undef MFMA128
#undef MK8
#undef STAGE6

  // epilogue: row = bm*128 + w*32 + m*16 + (lane>>4)*4 + i,
  //           z = bn>>4, col = (bn&15)*64 + n*16 + lr
  const int cr = lk4 << 2;
  const int z = bn >> 4;
  const int gr0 = bm * 128 + w * 32;
  const int gc0 = (bn & 15) * 64;
  if (z < 2) {
    unsigned char* C = (z == 0) ? Qf8 : Kf8;
#pragma unroll
    for (int m = 0; m < 2; ++m)
#pragma unroll
      for (int n = 0; n < 4; ++n)
#pragma unroll
        for (int i = 0; i < 4; ++i)
          C[(size_t)(gr0 + m * 16 + cr + i) * 1024 + (gc0 + n * 16 + lr)] =
              f32_to_fp8(acc[m][n][i]);
  } else {
    // Vt8[b][d][t] = V[b*512+t][d]; 4 consecutive t -> one uint store
#pragma unroll
    for (int m = 0; m < 2; ++m) {
      const int gr = gr0 + m * 16 + cr;
      const int b = gr >> 9, tt = gr & 511;
#pragma unroll
      for (int n = 0; n < 4; ++n) {
        const int d = gc0 + n * 16 + lr;
        unsigned int u = pk_fp8x4(acc[m][n][0], acc[m][n][1],
                                  acc[m][n][2], acc[m][n][3]);
        *(unsigned int*)(Vt8 + ((size_t)b * 1024 + d) * 512 + tt) = u;
      }
    }
  }
}

// ==== fp8 K=128 GEMM core, 128x128 tile, 256 threads, 1 barrier/phase ====
template <int KB, int NKT>
__device__ __forceinline__ void f8c128(const char* __restrict__ Ag,
                                       const char* __restrict__ Bg,
                                       char* lds, f32x4 (&acc)[4][4]) {
  const int tid = threadIdx.x;
  const int w = tid >> 6, lane = tid & 63;
  const int wm = w >> 1, wn = w & 1;
  const int lr = lane & 15, lk4 = lane >> 4;

  const int sc = ((tid & 3) ^ ((tid >> 3) & 3)) * 16;
  const char* pA = Ag + (size_t)(tid >> 2) * KB + sc;
  const char* pB = Bg + (size_t)(tid >> 2) * KB + sc;
  const size_t R64 = (size_t)64 * KB;

  const int swz = (lr >> 1) & 3;
  const int c0 = (lk4 & 1) * 2;
  const int cb0 = ((c0) ^ swz) * 16;
  const int cb1 = ((c0 + 1) ^ swz) * 16;
  const int panA = (lk4 >> 1) * 8192;
  const int panB = 16384 + (lk4 >> 1) * 8192;
  const int rowA = (wm * 64 + lr) * 64;
  const int rowB = (wn * 64 + lr) * 64;

#define STAGE8(DD)                                                            \
  do {                                                                        \
    char* dd_ = (DD);                                                         \
    gload_lds16(pA,            dd_ + tid * 16);                               \
    gload_lds16(pA + R64,      dd_ + 4096 + tid * 16);                        \
    gload_lds16(pA + 64,       dd_ + 8192 + tid * 16);                        \
    gload_lds16(pA + R64 + 64, dd_ + 12288 + tid * 16);                       \
    gload_lds16(pB,            dd_ + 16384 + tid * 16);                       \
    gload_lds16(pB + R64,      dd_ + 20480 + tid * 16);                       \
    gload_lds16(pB + 64,       dd_ + 24576 + tid * 16);                       \
    gload_lds16(pB + R64 + 64, dd_ + 28672 + tid * 16);                       \
    pA += 128; pB += 128;                                                     \
  } while (0)

#define MK8(D, OFF)                                                           \
  do {                                                                        \
    i32x4v lo_ = *(const i32x4v*)(sp + (OFF) + cb0);                          \
    i32x4v hi_ = *(const i32x4v*)(sp + (OFF) + cb1);                          \
    D[0] = lo_[0]; D[1] = lo_[1]; D[2] = lo_[2]; D[3] = lo_[3];               \
    D[4] = hi_[0]; D[5] = hi_[1]; D[6] = hi_[2]; D[7] = hi_[3];               \
  } while (0)

#define MFMA128(ACC, AV, BV)                                                  \
  asm("v_mfma_f32_16x16x128_f8f6f4 %0, %1, %2, %0"                            \
      : "+a"(ACC) : "v"(AV), "v"(BV))

  STAGE8(lds);   // prologue: K-tile 0 -> slot 0

#pragma unroll
  for (int t = 0; t < NKT; ++t) {
    const int slot = t & 1;
    asm volatile("s_waitcnt vmcnt(0)" ::: "memory");
    __builtin_amdgcn_s_barrier();
    __builtin_amdgcn_sched_barrier(0);
    if (t + 1 < NKT) STAGE8(lds + (slot ^ 1) * 32768);
    const char* sp = lds + slot * 32768;
    i32x8v a0, a1, b0, b1, b2, b3;
    MK8(a0, panA + rowA);          MK8(a1, panA + rowA + 1024);
    MK8(b0, panB + rowB);          MK8(b1, panB + rowB + 1024);
    MK8(b2, panB + rowB + 2048);   MK8(b3, panB + rowB + 3072);
    __builtin_amdgcn_s_setprio(1);
    MFMA128(acc[0][0], a0, b0); MFMA128(acc[0][1], a0, b1);
    MFMA128(acc[0][2], a0, b2); MFMA128(acc[0][3], a0, b3);
    MFMA128(acc[1][0], a1, b0); MFMA128(acc[1][1], a1, b1);
    MFMA128(acc[1][2], a1, b2); MFMA128(acc[1][3], a1, b3);
    __builtin_amdgcn_s_setprio(0);
    i32x8v a2, a3;
    MK8(a2, panA + rowA + 2048);   MK8(a3, panA + rowA + 3072);
    __builtin_amdgcn_s_setprio(1);
    MFMA128(acc[2][0], a2, b0); MFMA128(acc[2][1], a2, b1);
    MFMA128(acc[2][2], a2, b2); MFMA128(acc[2][3], a2, b3);
    MFMA128(acc[3][0], a3, b0); MFMA128(acc[3][1], a3, b1);
    MFMA128(acc[3][2], a3, b2); MFMA128(acc[3][3], a3, b3);
    __builtin_amdgcn_s_setprio(0);
    __builtin_amdgcn_sched_barrier(0);
  }

#undef MFMA128
#undef MK8
#undef STAGE8
}

// ============ S = Q K^T per batch (fp8 in, fp8 out) ============
__global__ __launch_bounds__(256, 2) void s_f8(
    const unsigned char* __restrict__ Qf8, const unsigned char* __restrict__ Kf8,
    unsigned char* __restrict__ S8) {
  __shared__ alignas(16) char smc[2][32768];
  const int bn = blockIdx.x, bm = blockIdx.y, b = blockIdx.z;
  const char* Ag = (const char*)Qf8 + ((size_t)b * 512 + bm * 128) * 1024;
  const char* Bg = (const char*)Kf8 + ((size_t)b * 512 + bn * 128) * 1024;
  f32x4 acc[4][4] = {};
  f8c128<1024, 8>(Ag, Bg, &smc[0][0], acc);

  const int tid = threadIdx.x;
  const int w = tid >> 6, lane = tid & 63;
  const int wm = w >> 1, wn = w & 1;
  const int lr = lane & 15, lk4 = lane >> 4;
  const int cr = lk4 << 2;
  unsigned char* Cp = S8 + (size_t)b * 262144;
  const int rbase = bm * 128 + wm * 64;
  const int cbase = bn * 128 + wn * 64;
#pragma unroll
  for (int m = 0; m < 4; ++m)
#pragma unroll
    for (int n = 0; n < 4; ++n)
#pragma unroll
      for (int i = 0; i < 4; ++i)
        Cp[(size_t)(rbase + m * 16 + cr + i) * 512 + (cbase + n * 16 + lr)] =
            f32_to_fp8(acc[m][n][i]);
}

// -------- row L2-normalize + softmax; attn f32 out + P fp8 (x256) --------
__global__ __launch_bounds__(256) void softmax_rows(const unsigned char* __restrict__ S8,
                                                    float* __restrict__ out,
                                                    unsigned char* __restrict__ P8) {
  const int w = threadIdx.x >> 6, lane = threadIdx.x & 63;
  const int r = blockIdx.x * 4 + w;          // global row 0..16383
  const int b = r >> 9, s = r & 511;
  uint2 v = *(const uint2*)(S8 + (size_t)r * 512 + lane * 8);
  float x[8];
#pragma unroll
  for (int i = 0; i < 4; ++i) x[i] = fp8_to_f32((v.x >> (8 * i)) & 0xffu);
#pragma unroll
  for (int i = 0; i < 4; ++i) x[4 + i] = fp8_to_f32((v.y >> (8 * i)) & 0xffu);
  float ss = 0.f;
#pragma unroll
  for (int i = 0; i < 8; ++i) ss += x[i] * x[i];
  ss = wave_sum(ss);
  const float inv = 1.0f / fmaxf(sqrtf(ss), 1e-12f);
  float mx = -1e30f;
#pragma unroll
  for (int i = 0; i < 8; ++i) { x[i] *= inv; mx = fmaxf(mx, x[i]); }
  mx = wave_max(mx);
  float se = 0.f;
#pragma unroll
  for (int i = 0; i < 8; ++i) { x[i] = __expf(x[i] - mx); se += x[i]; }
  se = wave_sum(se);
  const float rs = 1.0f / se;
#pragma unroll
  for (int i = 0; i < 8; ++i) x[i] *= rs;

  float* op = out + (size_t)b * 786432 + 524288 + (size_t)s * 512 + lane * 8;
  float4 o0 = {x[0], x[1], x[2], x[3]};
  float4 o1 = {x[4], x[5], x[6], x[7]};
  *(float4*)op = o0;
  *(float4*)(op + 4) = o1;
  uint2 pw;
  pw.x = pk_fp8x4(x[0] * 256.f, x[1] * 256.f, x[2] * 256.f, x[3] * 256.f);
  pw.y = pk_fp8x4(x[4] * 256.f, x[5] * 256.f, x[6] * 256.f, x[7] * 256.f);
  *(uint2*)(P8 + (size_t)r * 512 + lane * 8) = pw;
}

// ====== O = P V via Vt (fp8 in, fp8 out x16: acc*(16/256) = acc/16) ======
__global__ __launch_bounds__(256, 2) void pv_f8(
    const unsigned char* __restrict__ P8, const unsigned char* __restrict__ Vt8,
    unsigned char* __restrict__ O8) {
  __shared__ alignas(16) char smc[2][32768];
  const int bn = blockIdx.x, bm = blockIdx.y, b = blockIdx.z;
  const char* Ag = (const char*)P8 + ((size_t)b * 512 + bm * 128) * 512;
  const char* Bg = (const char*)Vt8 + ((size_t)b * 1024 + bn * 128) * 512;
  f32x4 acc[4][4] = {};
  f8c128<512, 4>(Ag, Bg, &smc[0][0], acc);

  const int tid = threadIdx.x;
  const int w = tid >> 6, lane = tid & 63;
  const int wm = w >> 1, wn = w & 1;
  const int lr = lane & 15, lk4 = lane >> 4;
  const int cr = lk4 << 2;
  const int grow = b * 512 + bm * 128 + wm * 64;
  const int cbase = bn * 128 + wn * 64;
#pragma unroll
  for (int m = 0; m < 4; ++m)
#pragma unroll
    for (int n = 0; n < 4; ++n)
#pragma unroll
      for (int i = 0; i < 4; ++i)
        O8[(size_t)(grow + m * 16 + cr + i) * 1024 + (cbase + n * 16 + lr)] =
            f32_to_fp8(acc[m][n][i] * 0.0625f);   // /256 then x16
}

// ------- residual + LayerNorm; O fp8 (x16) + Xb bf16 -> out f32 -------
__global__ __launch_bounds__(256) void ln_rows(const unsigned char* __restrict__ O8,
                                               const unsigned short* __restrict__ Xb,
                                               const float* __restrict__ gamma,
                                               const float* __restrict__ beta,
                                               float* __restrict__ out) {
  const int w = threadIdx.x >> 6, lane = threadIdx.x & 63;
  const int r = blockIdx.x * 4 + w;
  const int b = r >> 9, s = r & 511;
  const int col0 = lane * 16;                // 16 consecutive cols per lane
  uint4 o16 = *(const uint4*)(O8 + (size_t)r * 1024 + col0);
  US8 d0 = *(const US8*)(Xb + (size_t)r * 1024 + col0);
  US8 d1 = *(const US8*)(Xb + (size_t)r * 1024 + col0 + 8);
  float x[16];
  const unsigned int ov[4] = {o16.x, o16.y, o16.z, o16.w};
#pragma unroll
  for (int j = 0; j < 4; ++j)
#pragma unroll
    for (int k = 0; k < 4; ++k)
      x[j * 4 + k] = fp8_to_f32((ov[j] >> (8 * k)) & 0xffu) * 0.0625f;
#pragma unroll
  for (int k = 0; k < 8; ++k) x[k] += bf16_to_f32(d0.s[k]);
#pragma unroll
  for (int k = 0; k < 8; ++k) x[8 + k] += bf16_to_f32(d1.s[k]);

  float sm = 0.f, sq = 0.f;
#pragma unroll
  for (int i = 0; i < 16; ++i) { sm += x[i]; sq += x[i] * x[i]; }
  sm = wave_sum(sm);
  sq = wave_sum(sq);
  const float mean = sm * (1.0f / 1024.0f);
  const float var = sq * (1.0f / 1024.0f) - mean * mean;
  const float rstd = rsqrtf(var + 1e-6f);
  float* op = out + (size_t)b * 786432 + (size_t)s * 1024 + col0;
#pragma unroll
  for (int j = 0; j < 4; ++j) {
    float4 g = *(const float4*)(gamma + col0 + j * 4);
    float4 be = *(const float4*)(beta + col0 + j * 4);
    float4 y;
    y.x = (x[j * 4 + 0] - mean) * rstd * g.x + be.x;
    y.y = (x[j * 4 + 1] - mean) * rstd * g.y + be.y;
    y.z = (x[j * 4 + 2] - mean) * rstd * g.z + be.z;
    y.w = (x[j * 4 + 3] - mean) * rstd * g.w + be.w;
    *(float4*)(op + j * 4) = y;
  }
}

extern "C" void kernel_launch(void* const* d_in, const int* in_sizes, int n_in,
                              void* d_out, int out_size, void* d_ws, size_t ws_size,
                              hipStream_t stream) {
  const float* data  = (const float*)d_in[0];
  const float* wq    = (const float*)d_in[1];
  const float* wk    = (const float*)d_in[2];
  const float* wv    = (const float*)d_in[3];
  const float* gamma = (const float*)d_in[4];
  const float* beta  = (const float*)d_in[5];
  float* out = (float*)d_out;
  char* ws = (char*)d_ws;
  if (ws_size < WS_NEED) return;

  unsigned short* Xb  = (unsigned short*)(ws + WS_XB);
  unsigned int*   Xf8 = (unsigned int*)(ws + WS_XF8);
  unsigned int*   Wf8 = (unsigned int*)(ws + WS_WF8);
  unsigned char*  Qf8 = (unsigned char*)(ws + WS_QF8);
  unsigned char*  Kf8 = (unsigned char*)(ws + WS_KF8);
  unsigned char*  Vt8 = (unsigned char*)(ws + WS_VT8);
  unsigned char*  S8  = (unsigned char*)(ws + WS_S8);
  unsigned char*  P8  = (unsigned char*)(ws + WS_P8);
  unsigned char*  O8  = (unsigned char*)(ws + WS_O8);

  cvt_all<<<9728, 256, 0, stream>>>(data, wq, wk, wv, Xb, Xf8, Wf8);
  qkv_64<<<6144, 256, 0, stream>>>((const unsigned char*)Xf8,
                                   (const unsigned char*)Wf8, Qf8, Kf8, Vt8);
  s_f8<<<dim3(4, 4, 32), 256, 0, stream>>>(Qf8, Kf8, S8);
  softmax_rows<<<4096, 256, 0, stream>>>(S8, out, P8);
  pv_f8<<<dim3(8, 4, 32), 256, 0, stream>>>(P8, Vt8, O8);
  ln_rows<<<4096, 256, 0, stream>>>(O8, Xb, gamma, beta, out);
}

// Round 20
// 164.080 us; speedup vs baseline: 1.0252x; 1.0252x over previous
//
#include <hip/hip_runtime.h>
#include <hip/hip_bf16.h>

// ModalAttention fused pipeline, MI355X (gfx950).
//
// Math: attn/|global_min| followed by L2-normalize cancels any positive
// per-tensor scale (incl. /sqrt(h)) -> softmax input = s_row/||s_row||_2,
// s = q.k. No global-min reduction needed.
//
// Round 20: revert to the round-18 optimum (163.6us, best of 20 rounds).
// fp8 K=128 GEMM core (128x128 tile, 256 thr, 2 blocks/CU, 2-slot 32KB
// LDS, single-barrier phase, counted-vmcnt prologue); Q/K/Vt/S/P/O all
// fp8 (P x256, O x16); exact-decode fp8 bit-math; merged input casts.
// r19's 3-blk/CU variant regressed (TLP axis exhausted); this is the
// empirically best configuration across 9 structural variants.

typedef float f32x4 __attribute__((ext_vector_type(4)));
typedef int i32x4v __attribute__((ext_vector_type(4)));
typedef int i32x8v __attribute__((ext_vector_type(8)));

struct alignas(16) US8 { unsigned short s[8]; };
struct alignas(8)  US4 { unsigned short s[4]; };

// ---------------- workspace layout (bytes, disjoint) ----------------
#define WS_XB   0ull                        // data bf16 [16384][1024] 33.55MB
#define WS_XF8  33554432ull                 // data fp8  [16384][1024] 16.78MB
#define WS_WF8  50331648ull                 // wq,wk,wv fp8 [3][1024][1024] 3.15MB
#define WS_QF8  53477376ull                 // Q fp8 [16384][1024] 16.78MB
#define WS_KF8  70254592ull                 // K fp8 [16384][1024] 16.78MB
#define WS_VT8  87031808ull                 // V^T fp8 [32][1024][512] 16.78MB
#define WS_S8   103809024ull                // S fp8 [16384][512] 8.39MB
#define WS_P8   112197632ull                // P fp8 (x256) [16384][512] 8.39MB
#define WS_O8   120586240ull                // O fp8 (x16) [16384][1024] 16.78MB
#define WS_NEED 137363456ull

__device__ __forceinline__ unsigned short f32_to_bf16(float f) {
  unsigned int u = __builtin_bit_cast(unsigned int, f);
  u += 0x7fffu + ((u >> 16) & 1u);            // round-to-nearest-even
  return (unsigned short)(u >> 16);
}
__device__ __forceinline__ float bf16_to_f32(unsigned short h) {
  return __builtin_bit_cast(float, (unsigned int)h << 16);
}

__device__ __forceinline__ void gload_lds16(const void* g, void* lds) {
  __builtin_amdgcn_global_load_lds(
      (const __attribute__((address_space(1))) unsigned int*)g,
      (__attribute__((address_space(3))) unsigned int*)lds, 16, 0, 0);
}

__device__ __forceinline__ float wave_sum(float v) {
#pragma unroll
  for (int off = 32; off > 0; off >>= 1) v += __shfl_xor(v, off);
  return v;
}
__device__ __forceinline__ float wave_max(float v) {
#pragma unroll
  for (int off = 32; off > 0; off >>= 1) v = fmaxf(v, __shfl_xor(v, off));
  return v;
}

__device__ __forceinline__ unsigned int pk_fp8x4(float a, float b, float c, float d) {
  unsigned int v = 0;
  v = __builtin_amdgcn_cvt_pk_fp8_f32(a, b, v, false);  // bytes 0,1
  v = __builtin_amdgcn_cvt_pk_fp8_f32(c, d, v, true);   // bytes 2,3
  return v;
}
__device__ __forceinline__ unsigned char f32_to_fp8(float v) {
  return (unsigned char)(__builtin_amdgcn_cvt_pk_fp8_f32(v, v, 0, false) & 0xffu);
}
// exact e4m3 -> f32 (normals AND subnormals)
__device__ __forceinline__ float fp8_to_f32(unsigned int b) {
  unsigned int u = ((b & 0x80u) << 24) | ((b & 0x7Fu) << 20);
  return __builtin_bit_cast(float, u) * 0x1p120f;
}

// ------- merged cast: data f32->bf16+fp8, weights f32->fp8, one launch -----
__global__ __launch_bounds__(256) void cvt_all(const float* __restrict__ data,
                                               const float* __restrict__ wq,
                                               const float* __restrict__ wk,
                                               const float* __restrict__ wv,
                                               unsigned short* __restrict__ Xb,
                                               unsigned int* __restrict__ Xf8,
                                               unsigned int* __restrict__ Wf8) {
  const int bid = blockIdx.x;
  if (bid < 8192) {                 // data: 2097152 groups of 8
    int i = bid * 256 + threadIdx.x;
    const float4* sp = (const float4*)(data + (size_t)i * 8);
    float4 a = sp[0], b = sp[1];
    US8 u;
    u.s[0] = f32_to_bf16(a.x); u.s[1] = f32_to_bf16(a.y);
    u.s[2] = f32_to_bf16(a.z); u.s[3] = f32_to_bf16(a.w);
    u.s[4] = f32_to_bf16(b.x); u.s[5] = f32_to_bf16(b.y);
    u.s[6] = f32_to_bf16(b.z); u.s[7] = f32_to_bf16(b.w);
    *(US8*)(Xb + (size_t)i * 8) = u;
    uint2 w;
    w.x = pk_fp8x4(a.x, a.y, a.z, a.w);
    w.y = pk_fp8x4(b.x, b.y, b.z, b.w);
    *(uint2*)(Xf8 + (size_t)i * 2) = w;
  } else {                          // weights: 3 x 512 blocks
    const int r = bid - 8192;
    const int z = r >> 9;
    const float* src = (z == 0) ? wq : (z == 1) ? wk : wv;
    int i = (r & 511) * 256 + threadIdx.x;
    const float4* sp = (const float4*)(src + (size_t)i * 8);
    float4 a = sp[0], b = sp[1];
    uint2 w;
    w.x = pk_fp8x4(a.x, a.y, a.z, a.w);
    w.y = pk_fp8x4(b.x, b.y, b.z, b.w);
    *(uint2*)(Wf8 + (size_t)z * 262144 + (size_t)i * 2) = w;
  }
}

// ==== fp8 K=128 GEMM core, 128x128 tile, 256 threads, 1 barrier/phase ====
template <int KB, int NKT>
__device__ __forceinline__ void f8c128(const char* __restrict__ Ag,
                                       const char* __restrict__ Bg,
                                       char* lds, f32x4 (&acc)[4][4]) {
  const int tid = threadIdx.x;
  const int w = tid >> 6, lane = tid & 63;
  const int wm = w >> 1, wn = w & 1;
  const int lr = lane & 15, lk4 = lane >> 4;

  const int sc = ((tid & 3) ^ ((tid >> 3) & 3)) * 16;
  const char* pA = Ag + (size_t)(tid >> 2) * KB + sc;
  const char* pB = Bg + (size_t)(tid >> 2) * KB + sc;
  const size_t R64 = (size_t)64 * KB;

  const int swz = (lr >> 1) & 3;
  const int c0 = (lk4 & 1) * 2;
  const int cb0 = ((c0) ^ swz) * 16;
  const int cb1 = ((c0 + 1) ^ swz) * 16;
  const int panA = (lk4 >> 1) * 8192;
  const int panB = 16384 + (lk4 >> 1) * 8192;
  const int rowA = (wm * 64 + lr) * 64;
  const int rowB = (wn * 64 + lr) * 64;

#define STAGE8(DD)                                                            \
  do {                                                                        \
    char* dd_ = (DD);                                                         \
    gload_lds16(pA,            dd_ + tid * 16);                               \
    gload_lds16(pA + R64,      dd_ + 4096 + tid * 16);                        \
    gload_lds16(pA + 64,       dd_ + 8192 + tid * 16);                        \
    gload_lds16(pA + R64 + 64, dd_ + 12288 + tid * 16);                       \
    gload_lds16(pB,            dd_ + 16384 + tid * 16);                       \
    gload_lds16(pB + R64,      dd_ + 20480 + tid * 16);                       \
    gload_lds16(pB + 64,       dd_ + 24576 + tid * 16);                       \
    gload_lds16(pB + R64 + 64, dd_ + 28672 + tid * 16);                       \
    pA += 128; pB += 128;                                                     \
  } while (0)

#define MK8(D, OFF)                                                           \
  do {                                                                        \
    i32x4v lo_ = *(const i32x4v*)(sp + (OFF) + cb0);                          \
    i32x4v hi_ = *(const i32x4v*)(sp + (OFF) + cb1);                          \
    D[0] = lo_[0]; D[1] = lo_[1]; D[2] = lo_[2]; D[3] = lo_[3];               \
    D[4] = hi_[0]; D[5] = hi_[1]; D[6] = hi_[2]; D[7] = hi_[3];               \
  } while (0)

#define MFMA128(ACC, AV, BV)                                                  \
  asm("v_mfma_f32_16x16x128_f8f6f4 %0, %1, %2, %0"                            \
      : "+a"(ACC) : "v"(AV), "v"(BV))

  STAGE8(lds);   // prologue: K-tile 0 -> slot 0 (8 loads outstanding)

#pragma unroll
  for (int t = 0; t < NKT; ++t) {
    const int slot = t & 1;
    // single sync point: own slot-t loads drained, then converge.
    asm volatile("s_waitcnt vmcnt(0)" ::: "memory");
    __builtin_amdgcn_s_barrier();
    __builtin_amdgcn_sched_barrier(0);
    // stage t+1 into the OTHER slot: safe — every wave's phase t-1 reads
    // of that slot precede its barrier arrival in program order.
    if (t + 1 < NKT) STAGE8(lds + (slot ^ 1) * 32768);
    const char* sp = lds + slot * 32768;
    i32x8v a0, a1, b0, b1, b2, b3;
    MK8(a0, panA + rowA);          MK8(a1, panA + rowA + 1024);
    MK8(b0, panB + rowB);          MK8(b1, panB + rowB + 1024);
    MK8(b2, panB + rowB + 2048);   MK8(b3, panB + rowB + 3072);
    __builtin_amdgcn_s_setprio(1);
    MFMA128(acc[0][0], a0, b0); MFMA128(acc[0][1], a0, b1);
    MFMA128(acc[0][2], a0, b2); MFMA128(acc[0][3], a0, b3);
    MFMA128(acc[1][0], a1, b0); MFMA128(acc[1][1], a1, b1);
    MFMA128(acc[1][2], a1, b2); MFMA128(acc[1][3], a1, b3);
    __builtin_amdgcn_s_setprio(0);
    i32x8v a2, a3;
    MK8(a2, panA + rowA + 2048);   MK8(a3, panA + rowA + 3072);
    __builtin_amdgcn_s_setprio(1);
    MFMA128(acc[2][0], a2, b0); MFMA128(acc[2][1], a2, b1);
    MFMA128(acc[2][2], a2, b2); MFMA128(acc[2][3], a2, b3);
    MFMA128(acc[3][0], a3, b0); MFMA128(acc[3][1], a3, b1);
    MFMA128(acc[3][2], a3, b2); MFMA128(acc[3][3], a3, b3);
    __builtin_amdgcn_s_setprio(0);
    __builtin_amdgcn_sched_barrier(0);
  }

#undef MFMA128
#undef MK8
#undef STAGE8
}

// ============ QKV: fp8 in/out (Q,K row-major; Vt transposed) ========
__global__ __launch_bounds__(256, 2) void qkv_128(
    const unsigned char* __restrict__ Xf8, const unsigned char* __restrict__ Wf8,
    unsigned char* __restrict__ Qf8, unsigned char* __restrict__ Kf8,
    unsigned char* __restrict__ Vt8) {
  __shared__ alignas(16) char smc[2][32768];
  const int bid = blockIdx.x;
  const int wg = (bid & 7) * 384 + (bid >> 3);   // bijective, 3072 % 8 == 0
  const int bm = wg / 24, bn = wg % 24;
  const char* Ag = (const char*)Xf8 + (size_t)bm * 128 * 1024;
  const char* Bg = (const char*)Wf8 + (size_t)bn * 128 * 1024;
  f32x4 acc[4][4] = {};
  f8c128<1024, 8>(Ag, Bg, &smc[0][0], acc);

  const int tid = threadIdx.x;
  const int w = tid >> 6, lane = tid & 63;
  const int wm = w >> 1, wn = w & 1;
  const int lr = lane & 15, lk4 = lane >> 4;
  const int cr = lk4 << 2;
  const int z = bn >> 3;                       // 0=Q 1=K 2=V
  const int gr0 = bm * 128 + wm * 64;
  const int gc0 = (bn & 7) * 128 + wn * 64;
  if (z < 2) {
    unsigned char* C = (z == 0) ? Qf8 : Kf8;
#pragma unroll
    for (int m = 0; m < 4; ++m)
#pragma unroll
      for (int n = 0; n < 4; ++n)
#pragma unroll
        for (int i = 0; i < 4; ++i)
          C[(size_t)(gr0 + m * 16 + cr + i) * 1024 + (gc0 + n * 16 + lr)] =
              f32_to_fp8(acc[m][n][i]);
  } else {
    // Vt8[b][d][t] = V[b*512+t][d]; 4 consecutive t -> one uint store
#pragma unroll
    for (int m = 0; m < 4; ++m) {
      const int gr = gr0 + m * 16 + cr;
      const int b = gr >> 9, tt = gr & 511;
#pragma unroll
      for (int n = 0; n < 4; ++n) {
        const int d = gc0 + n * 16 + lr;
        unsigned int u = pk_fp8x4(acc[m][n][0], acc[m][n][1],
                                  acc[m][n][2], acc[m][n][3]);
        *(unsigned int*)(Vt8 + ((size_t)b * 1024 + d) * 512 + tt) = u;
      }
    }
  }
}

// ============ S = Q K^T per batch (fp8 in, fp8 out) ============
__global__ __launch_bounds__(256, 2) void s_f8(
    const unsigned char* __restrict__ Qf8, const unsigned char* __restrict__ Kf8,
    unsigned char* __restrict__ S8) {
  __shared__ alignas(16) char smc[2][32768];
  const int bn = blockIdx.x, bm = blockIdx.y, b = blockIdx.z;
  const char* Ag = (const char*)Qf8 + ((size_t)b * 512 + bm * 128) * 1024;
  const char* Bg = (const char*)Kf8 + ((size_t)b * 512 + bn * 128) * 1024;
  f32x4 acc[4][4] = {};
  f8c128<1024, 8>(Ag, Bg, &smc[0][0], acc);

  const int tid = threadIdx.x;
  const int w = tid >> 6, lane = tid & 63;
  const int wm = w >> 1, wn = w & 1;
  const int lr = lane & 15, lk4 = lane >> 4;
  const int cr = lk4 << 2;
  unsigned char* Cp = S8 + (size_t)b * 262144;
  const int rbase = bm * 128 + wm * 64;
  const int cbase = bn * 128 + wn * 64;
#pragma unroll
  for (int m = 0; m < 4; ++m)
#pragma unroll
    for (int n = 0; n < 4; ++n)
#pragma unroll
      for (int i = 0; i < 4; ++i)
        Cp[(size_t)(rbase + m * 16 + cr + i) * 512 + (cbase + n * 16 + lr)] =
            f32_to_fp8(acc[m][n][i]);
}

// -------- row L2-normalize + softmax; attn f32 out + P fp8 (x256) --------
__global__ __launch_bounds__(256) void softmax_rows(const unsigned char* __restrict__ S8,
                                                    float* __restrict__ out,
                                                    unsigned char* __restrict__ P8) {
  const int w = threadIdx.x >> 6, lane = threadIdx.x & 63;
  const int r = blockIdx.x * 4 + w;          // global row 0..16383
  const int b = r >> 9, s = r & 511;
  uint2 v = *(const uint2*)(S8 + (size_t)r * 512 + lane * 8);
  float x[8];
#pragma unroll
  for (int i = 0; i < 4; ++i) x[i] = fp8_to_f32((v.x >> (8 * i)) & 0xffu);
#pragma unroll
  for (int i = 0; i < 4; ++i) x[4 + i] = fp8_to_f32((v.y >> (8 * i)) & 0xffu);
  float ss = 0.f;
#pragma unroll
  for (int i = 0; i < 8; ++i) ss += x[i] * x[i];
  ss = wave_sum(ss);
  const float inv = 1.0f / fmaxf(sqrtf(ss), 1e-12f);
  float mx = -1e30f;
#pragma unroll
  for (int i = 0; i < 8; ++i) { x[i] *= inv; mx = fmaxf(mx, x[i]); }
  mx = wave_max(mx);
  float se = 0.f;
#pragma unroll
  for (int i = 0; i < 8; ++i) { x[i] = __expf(x[i] - mx); se += x[i]; }
  se = wave_sum(se);
  const float rs = 1.0f / se;
#pragma unroll
  for (int i = 0; i < 8; ++i) x[i] *= rs;

  float* op = out + (size_t)b * 786432 + 524288 + (size_t)s * 512 + lane * 8;
  float4 o0 = {x[0], x[1], x[2], x[3]};
  float4 o1 = {x[4], x[5], x[6], x[7]};
  *(float4*)op = o0;
  *(float4*)(op + 4) = o1;
  // P stored x256 (attn ~2e-3 is on e4m3's subnormal floor; x256 -> normal)
  uint2 pw;
  pw.x = pk_fp8x4(x[0] * 256.f, x[1] * 256.f, x[2] * 256.f, x[3] * 256.f);
  pw.y = pk_fp8x4(x[4] * 256.f, x[5] * 256.f, x[6] * 256.f, x[7] * 256.f);
  *(uint2*)(P8 + (size_t)r * 512 + lane * 8) = pw;
}

// ====== O = P V via Vt (fp8 in, fp8 out x16: acc*(16/256) = acc/16) ======
__global__ __launch_bounds__(256, 2) void pv_f8(
    const unsigned char* __restrict__ P8, const unsigned char* __restrict__ Vt8,
    unsigned char* __restrict__ O8) {
  __shared__ alignas(16) char smc[2][32768];
  const int bn = blockIdx.x, bm = blockIdx.y, b = blockIdx.z;
  const char* Ag = (const char*)P8 + ((size_t)b * 512 + bm * 128) * 512;
  const char* Bg = (const char*)Vt8 + ((size_t)b * 1024 + bn * 128) * 512;
  f32x4 acc[4][4] = {};
  f8c128<512, 4>(Ag, Bg, &smc[0][0], acc);

  const int tid = threadIdx.x;
  const int w = tid >> 6, lane = tid & 63;
  const int wm = w >> 1, wn = w & 1;
  const int lr = lane & 15, lk4 = lane >> 4;
  const int cr = lk4 << 2;
  const int grow = b * 512 + bm * 128 + wm * 64;
  const int cbase = bn * 128 + wn * 64;
#pragma unroll
  for (int m = 0; m < 4; ++m)
#pragma unroll
    for (int n = 0; n < 4; ++n)
#pragma unroll
      for (int i = 0; i < 4; ++i)
        O8[(size_t)(grow + m * 16 + cr + i) * 1024 + (cbase + n * 16 + lr)] =
            f32_to_fp8(acc[m][n][i] * 0.0625f);   // /256 then x16
}

// ------- residual + LayerNorm; O fp8 (x16) + Xb bf16 -> out f32 -------
__global__ __launch_bounds__(256) void ln_rows(const unsigned char* __restrict__ O8,
                                               const unsigned short* __restrict__ Xb,
                                               const float* __restrict__ gamma,
                                               const float* __restrict__ beta,
                                               float* __restrict__ out) {
  const int w = threadIdx.x >> 6, lane = threadIdx.x & 63;
  const int r = blockIdx.x * 4 + w;
  const int b = r >> 9, s = r & 511;
  const int col0 = lane * 16;                // 16 consecutive cols per lane
  uint4 o16 = *(const uint4*)(O8 + (size_t)r * 1024 + col0);
  US8 d0 = *(const US8*)(Xb + (size_t)r * 1024 + col0);
  US8 d1 = *(const US8*)(Xb + (size_t)r * 1024 + col0 + 8);
  float x[16];
  const unsigned int ov[4] = {o16.x, o16.y, o16.z, o16.w};
#pragma unroll
  for (int j = 0; j < 4; ++j)
#pragma unroll
    for (int k = 0; k < 4; ++k)
      x[j * 4 + k] = fp8_to_f32((ov[j] >> (8 * k)) & 0xffu) * 0.0625f;
#pragma unroll
  for (int k = 0; k < 8; ++k) x[k] += bf16_to_f32(d0.s[k]);
#pragma unroll
  for (int k = 0; k < 8; ++k) x[8 + k] += bf16_to_f32(d1.s[k]);

  float sm = 0.f, sq = 0.f;
#pragma unroll
  for (int i = 0; i < 16; ++i) { sm += x[i]; sq += x[i] * x[i]; }
  sm = wave_sum(sm);
  sq = wave_sum(sq);
  const float mean = sm * (1.0f / 1024.0f);
  const float var = sq * (1.0f / 1024.0f) - mean * mean;
  const float rstd = rsqrtf(var + 1e-6f);
  float* op = out + (size_t)b * 786432 + (size_t)s * 1024 + col0;
#pragma unroll
  for (int j = 0; j < 4; ++j) {
    float4 g = *(const float4*)(gamma + col0 + j * 4);
    float4 be = *(const float4*)(beta + col0 + j * 4);
    float4 y;
    y.x = (x[j * 4 + 0] - mean) * rstd * g.x + be.x;
    y.y = (x[j * 4 + 1] - mean) * rstd * g.y + be.y;
    y.z = (x[j * 4 + 2] - mean) * rstd * g.z + be.z;
    y.w = (x[j * 4 + 3] - mean) * rstd * g.w + be.w;
    *(float4*)(op + j * 4) = y;
  }
}

extern "C" void kernel_launch(void* const* d_in, const int* in_sizes, int n_in,
                              void* d_out, int out_size, void* d_ws, size_t ws_size,
                              hipStream_t stream) {
  const float* data  = (const float*)d_in[0];
  const float* wq    = (const float*)d_in[1];
  const float* wk    = (const float*)d_in[2];
  const float* wv    = (const float*)d_in[3];
  const float* gamma = (const float*)d_in[4];
  const float* beta  = (const float*)d_in[5];
  float* out = (float*)d_out;
  char* ws = (char*)d_ws;
  if (ws_size < WS_NEED) return;

  unsigned short* Xb  = (unsigned short*)(ws + WS_XB);
  unsigned int*   Xf8 = (unsigned int*)(ws + WS_XF8);
  unsigned int*   Wf8 = (unsigned int*)(ws + WS_WF8);
  unsigned char*  Qf8 = (unsigned char*)(ws + WS_QF8);
  unsigned char*  Kf8 = (unsigned char*)(ws + WS_KF8);
  unsigned char*  Vt8 = (unsigned char*)(ws + WS_VT8);
  unsigned char*  S8  = (unsigned char*)(ws + WS_S8);
  unsigned char*  P8  = (unsigned char*)(ws + WS_P8);
  unsigned char*  O8  = (unsigned char*)(ws + WS_O8);

  cvt_all<<<9728, 256, 0, stream>>>(data, wq, wk, wv, Xb, Xf8, Wf8);
  qkv_128<<<3072, 256, 0, stream>>>((const unsigned char*)Xf8,
                                    (const unsigned char*)Wf8, Qf8, Kf8, Vt8);
  s_f8<<<dim3(4, 4, 32), 256, 0, stream>>>(Qf8, Kf8, S8);
  softmax_rows<<<4096, 256, 0, stream>>>(S8, out, P8);
  pv_f8<<<dim3(8, 4, 32), 256, 0, stream>>>(P8, Vt8, O8);
  ln_rows<<<4096, 256, 0, stream>>>(O8, Xb, gamma, beta, out);
}